// Round 2
// baseline (3810.151 us; speedup 1.0000x reference)
//
#include <hip/hip_runtime.h>
#include <stdint.h>

typedef unsigned short u16;
typedef unsigned int   u32;
typedef __attribute__((ext_vector_type(8))) short short8;
typedef __attribute__((ext_vector_type(4))) float f32x4;

#define CAP   52
#define CAPW  26

__device__ __forceinline__ u16 rne_bf16(float f){
  u32 u = __float_as_uint(f);
  u32 r = (u + 0x7fffu + ((u >> 16) & 1u)) >> 16;
  return (u16)r;
}
__device__ __forceinline__ float bf16_to_f(u16 h){
  return __uint_as_float(((u32)h) << 16);
}
__device__ __forceinline__ float tanh_fast(float x){
  float e = __expf(2.0f * x);
  return 1.0f - 2.0f / (e + 1.0f);
}

// ---------------------------------------------------------------------------
// A-pack: [xhi fbhi | xlo fblo], row m = b*1024+s, K=2048 bf16 bits
// ---------------------------------------------------------------------------
__global__ __launch_bounds__(256) void pack_a_k(const float* __restrict__ x,
                                                const float* __restrict__ fb,
                                                u16* __restrict__ A){
  int idx = blockIdx.x * 256 + threadIdx.x;          // 16384*512
  int m = idx >> 9, d = idx & 511;
  float xv = x[idx];
  float fv = fb[idx];
  u16 xh = rne_bf16(xv); u16 xl = rne_bf16(xv - bf16_to_f(xh));
  u16 fh = rne_bf16(fv); u16 fl = rne_bf16(fv - bf16_to_f(fh));
  size_t base = (size_t)m * 2048;
  A[base + d]        = xh;
  A[base + 512 + d]  = fh;
  A[base + 1024 + d] = xl;
  A[base + 1536 + d] = fl;
}

// ---------------------------------------------------------------------------
// B-pack: K=3072: [Winhi Wfbhi | Winhi Wfbhi | Winlo Wfblo]
// ---------------------------------------------------------------------------
__global__ __launch_bounds__(256) void pack_b_k(const float* __restrict__ Win,
                                                const float* __restrict__ Wfb,
                                                u16* __restrict__ Bm){
  int idx = blockIdx.x * 256 + threadIdx.x;          // 2048*512
  int n = idx >> 9, d = idx & 511;
  float iv = Win[idx];
  float fv = Wfb[idx];
  u16 ih = rne_bf16(iv); u16 il = rne_bf16(iv - bf16_to_f(ih));
  u16 fh = rne_bf16(fv); u16 fl = rne_bf16(fv - bf16_to_f(fh));
  size_t base = (size_t)n * 3072;
  Bm[base + d]        = ih;
  Bm[base + 512 + d]  = fh;
  Bm[base + 1024 + d] = ih;
  Bm[base + 1536 + d] = fh;
  Bm[base + 2048 + d] = il;
  Bm[base + 2560 + d] = fl;
}

// ---------------------------------------------------------------------------
// Drive GEMM, writes drive PERMUTED: column colmap[n] gets drive(row n).
// ---------------------------------------------------------------------------
#define GLDS(gp, lp) __builtin_amdgcn_global_load_lds( \
    (const __attribute__((address_space(1))) void*)(gp), \
    (__attribute__((address_space(3))) void*)(lp), 16, 0, 0)

__global__ __launch_bounds__(256) void gemm_k(const u16* __restrict__ A,
                                              const u16* __restrict__ Bm,
                                              const int* __restrict__ colmap,
                                              float* __restrict__ C){
  __shared__ __align__(16) u16 As[128 * 32];
  __shared__ __align__(16) u16 Bs[128 * 32];
  const int tid = threadIdx.x;
  const int w = tid >> 6, l = tid & 63;
  const int bid = blockIdx.x;
  const int mt = bid >> 4, nt = bid & 15;
  const int m0 = mt * 128, n0 = nt * 128;
  const int srow = tid >> 2;
  const int scol = (tid & 3) * 8;
  const int wr = w & 1, wc = w >> 1;
  const int lhi = l >> 4, llo = l & 15;

  f32x4 acc[4][4];
  #pragma unroll
  for (int i = 0; i < 4; i++)
    #pragma unroll
    for (int j = 0; j < 4; j++)
      acc[i][j] = (f32x4){0.f, 0.f, 0.f, 0.f};

  for (int kt = 0; kt < 96; ++kt){
    int k = kt * 32;
    int keff = (k >= 2048) ? (k - 2048) : k;
    #pragma unroll
    for (int r = 0; r < 2; r++){
      const u16* ga = A  + (size_t)(m0 + r * 64 + srow) * 2048 + keff + scol;
      GLDS(ga, &As[r * 2048 + w * 512]);
      const u16* gb = Bm + (size_t)(n0 + r * 64 + srow) * 3072 + k + scol;
      GLDS(gb, &Bs[r * 2048 + w * 512]);
    }
    __syncthreads();
    short8 af[4], bf[4];
    #pragma unroll
    for (int i = 0; i < 4; i++){
      af[i] = *(const short8*)&As[(wr * 64 + i * 16 + llo) * 32 + lhi * 8];
      bf[i] = *(const short8*)&Bs[(wc * 64 + i * 16 + llo) * 32 + lhi * 8];
    }
    #pragma unroll
    for (int i = 0; i < 4; i++)
      #pragma unroll
      for (int j = 0; j < 4; j++)
        acc[i][j] = __builtin_amdgcn_mfma_f32_16x16x32_bf16(af[i], bf[j], acc[i][j], 0, 0, 0);
    __syncthreads();
  }
  int cmj[4];
  #pragma unroll
  for (int j = 0; j < 4; j++) cmj[j] = colmap[n0 + wc * 64 + j * 16 + llo];
  #pragma unroll
  for (int i = 0; i < 4; i++)
    #pragma unroll
    for (int j = 0; j < 4; j++)
      #pragma unroll
      for (int rg = 0; rg < 4; rg++){
        int mr = m0 + wr * 64 + i * 16 + lhi * 4 + rg;
        C[(size_t)mr * 2048 + cmj[j]] = acc[i][j][rg];
      }
}

// ---------------------------------------------------------------------------
// Sparse build: count nnz per row (one wave per row)
// ---------------------------------------------------------------------------
__global__ __launch_bounds__(256) void count_k(const float* __restrict__ W,
                                               int* __restrict__ nnz){
  int gt = blockIdx.x * 256 + threadIdx.x;
  int row = gt >> 6, l = gt & 63;
  const float* wr = W + (size_t)row * 2048;
  int c = 0;
  for (int i = 0; i < 32; i++) c += (wr[i * 64 + l] != 0.0f) ? 1 : 0;
  for (int off = 32; off; off >>= 1) c += __shfl_down(c, off, 64);
  if (l == 0) nnz[row] = c;
}

// ---------------------------------------------------------------------------
// Counting-sort rows desc by nnz, pair p <-> 2047-p; emit colmap for the
// permuted-drive GEMM epilogue.
// ---------------------------------------------------------------------------
__global__ __launch_bounds__(1024) void sort_k(const int* __restrict__ nnz,
                                               u32* __restrict__ rowsp,
                                               int* __restrict__ L1a,
                                               int* __restrict__ colmap){
  __shared__ int hist[64], off[64], cur[64];
  __shared__ int order[2048];
  int tid = threadIdx.x;
  if (tid < 64){ hist[tid] = 0; cur[tid] = 0; }
  __syncthreads();
  for (int r = tid; r < 2048; r += 1024){
    int b = nnz[r]; if (b > 63) b = 63;
    atomicAdd(&hist[b], 1);
  }
  __syncthreads();
  if (tid == 0){
    int run = 0;
    for (int b = 63; b >= 0; b--){ off[b] = run; run += hist[b]; }
  }
  __syncthreads();
  for (int r = tid; r < 2048; r += 1024){
    int b = nnz[r]; if (b > 63) b = 63;
    int pos = off[b] + atomicAdd(&cur[b], 1);
    order[pos] = r;
  }
  __syncthreads();
  int rA = order[tid], rB = order[2047 - tid];
  rowsp[tid] = (u32)rA | ((u32)rB << 16);
  L1a[tid] = nnz[rA];
  colmap[rA] = tid;
  colmap[rB] = tid + 1024;
}

// ---------------------------------------------------------------------------
// Fill per-thread chunks (slot-major): [0,L1)=rowA, [L1,..)=rowB, pad to CAP
// ---------------------------------------------------------------------------
__global__ __launch_bounds__(256) void fill_k(const float* __restrict__ W,
                                              const u32* __restrict__ rowsp,
                                              float* __restrict__ valw,
                                              u32* __restrict__ col32){
  int gt = blockIdx.x * 256 + threadIdx.x;
  int p = gt >> 6, l = gt & 63;
  u32 rp = rowsp[p];
  int rA = (int)(rp & 0xffffu), rB = (int)(rp >> 16);
  int base = 0;
  for (int h = 0; h < 2; h++){
    int row = h ? rB : rA;
    const float* wr = W + (size_t)row * 2048;
    int cnt = 0;
    for (int i = 0; i < 32; i++){
      int c = i * 64 + l;
      float v = wr[c];
      unsigned long long m = __ballot(v != 0.0f);
      int pre = __popcll(m & ((1ull << l) - 1ull));
      if (v != 0.0f){
        int s = base + cnt + pre;
        if (s < CAP){
          valw[s * 1024 + p] = v;
          col32[s * 1024 + p] = (u32)c;
        }
      }
      cnt += __popcll(m);
    }
    base += cnt;
  }
  for (int s = base + l; s < CAP; s += 64){
    valw[s * 1024 + p] = 0.0f;
    col32[s * 1024 + p] = 0u;
  }
}

// ---------------------------------------------------------------------------
// Bank-balance: per thread, per segment ([0,L1) and [L1,CAP)), counting-sort
// items by LDS bank (col&31) then rotate by lane*len/64 so that at each slot
// the 64 lanes walk a staggered bank ramp (~2 lanes/bank = conflict-free).
// Emits val2 (slot-major) and cw2 (packed byte-offsets col<<2, 2 per word).
// Runs once; scratch-heavy is fine.
// ---------------------------------------------------------------------------
__global__ __launch_bounds__(256) void reorder_k(const float* __restrict__ valw,
                                                 const u32* __restrict__ col32,
                                                 const int* __restrict__ L1a,
                                                 float* __restrict__ val2,
                                                 u32* __restrict__ cw2){
  int p = blockIdx.x * 256 + threadIdx.x;   // 1024 threads total
  float v[CAP]; int c[CAP];
  float tv[CAP]; int tc[CAP];
  for (int k = 0; k < CAP; k++){ v[k] = valw[k * 1024 + p]; c[k] = (int)col32[k * 1024 + p]; }
  int L1 = L1a[p];
  int lane = p & 63;
  int b0 = 0;
  for (int s = 0; s < 2; s++){
    int b1 = s ? CAP : L1;
    int len = b1 - b0;
    if (len > 0){
      int cnt[32], st_[32], cur[32];
      for (int b = 0; b < 32; b++){ cnt[b] = 0; cur[b] = 0; }
      for (int i = b0; i < b1; i++) cnt[c[i] & 31]++;
      int run = 0;
      for (int b = 0; b < 32; b++){ st_[b] = run; run += cnt[b]; }
      for (int i = b0; i < b1; i++){
        int b = c[i] & 31;
        int q = st_[b] + (cur[b]++);
        tv[q] = v[i]; tc[q] = c[i];
      }
      int off = (lane * len) >> 6;
      for (int q = 0; q < len; q++){
        int src = q + off; if (src >= len) src -= len;
        v[b0 + q] = tv[src]; c[b0 + q] = tc[src];
      }
    }
    b0 = b1;
  }
  for (int k = 0; k < CAP; k++) val2[k * 1024 + p] = v[k];
  for (int j = 0; j < CAPW; j++)
    cw2[j * 1024 + p] = ((u32)(c[2 * j] << 2)) | (((u32)(c[2 * j + 1] << 2)) << 16);
}

// ---------------------------------------------------------------------------
// Recurrent kernel: 16 WGs (1 batch/CU), 1024 thr, state in LDS, sparse W in
// registers. __launch_bounds__(1024,4) -> VGPR cap 128 (16-wave block needs
// <=128 anyway; default heuristic chose 64 and spilled val[]/cw[] -> 67 GB
// scratch fetch in R1). Drive arrives PERMUTED (coalesced read); final state
// stored coalesced from LDS.
// ---------------------------------------------------------------------------
__global__ __launch_bounds__(1024, 4) void rnn_k(float* __restrict__ out,
                                                 const float* __restrict__ init,
                                                 const float* __restrict__ valw,
                                                 const u32* __restrict__ cwg,
                                                 const u32* __restrict__ rowsp,
                                                 const int* __restrict__ L1a){
  const int tid = threadIdx.x, b = blockIdx.x;
  float val[CAP]; u32 cw[CAPW];
  #pragma unroll
  for (int k = 0; k < CAP; k++) val[k] = valw[k * 1024 + tid];
  #pragma unroll
  for (int j = 0; j < CAPW; j++) cw[j] = cwg[j * 1024 + tid];
  u32 rp = rowsp[tid];
  int rA = (int)(rp & 0xffffu), rB = (int)(rp >> 16);
  int L1 = L1a[tid];

  __shared__ float st[2048];
  st[tid]        = init[(size_t)b * 2048 + tid];
  st[tid + 1024] = init[(size_t)b * 2048 + tid + 1024];
  __syncthreads();
  const char* stb = (const char*)st;

  float* ob = out + (size_t)b * 1024 * 2048;
  for (int t = 0; t < 1024; t++){
    float* orow = ob + (size_t)t * 2048;
    float dA = orow[tid];           // permuted drive: coalesced
    float dB = orow[tid + 1024];
    float aAll = 0.f, aA = 0.f;
    #pragma unroll
    for (int k = 0; k < CAP; k++){
      u32 off = (k & 1) ? (cw[k >> 1] >> 16) : (cw[k >> 1] & 0xffffu);
      float sv = *(const float*)(stb + off);
      float pv = val[k] * sv;
      aAll += pv;
      aA += (k < L1) ? pv : 0.0f;
    }
    float preA = aA + dA;                 // consume drive BEFORE barrier
    float preB = (aAll - aA) + dB;
    __syncthreads();                      // all st reads done
    float sA = tanh_fast(preA);
    float sB = tanh_fast(preB);
    st[rA] = sA; st[rB] = sB;
    __syncthreads();                      // new state visible
    orow[tid] = st[tid];                  // coalesced store, standard layout
    orow[tid + 1024] = st[tid + 1024];
  }
}

// ---------------------------------------------------------------------------
extern "C" void kernel_launch(void* const* d_in, const int* in_sizes, int n_in,
                              void* d_out, int out_size, void* d_ws, size_t ws_size,
                              hipStream_t stream) {
  const float* x    = (const float*)d_in[0];
  const float* fb   = (const float*)d_in[1];
  const float* init = (const float*)d_in[2];
  const float* Wres = (const float*)d_in[3];
  const float* Win  = (const float*)d_in[4];
  const float* Wfb  = (const float*)d_in[5];
  float* out = (float*)d_out;

  char* w8 = (char*)d_ws;
  u16*  A_pack = (u16*)(w8);                       // 0         .. 67108864
  u16*  B_pack = (u16*)(w8 + 67108864);            // 12582912  -> 79691776
  float* valw  = (float*)(w8 + 79691776);          // 212992    -> 79904768
  u32*  col32  = (u32*) (w8 + 79904768);           // 212992    -> 80117760
  int*  colmap = (int*) (w8 + 80117760);           // 8192      -> 80125952
  int*  nnz    = (int*) (w8 + 80125952);           // 8192      -> 80134144
  u32*  rowsp  = (u32*) (w8 + 80134144);           // 4096      -> 80138240
  int*  L1a    = (int*) (w8 + 80138240);           // 4096      -> 80142336
  // val2/cw2 alias A_pack (dead after gemm_k; reorder_k runs after gemm_k)
  float* val2  = (float*)(w8);                     // 212992
  u32*  cw2    = (u32*) (w8 + 212992);             // 106496

  pack_a_k<<<32768, 256, 0, stream>>>(x, fb, A_pack);
  pack_b_k<<<4096, 256, 0, stream>>>(Win, Wfb, B_pack);
  count_k<<<512, 256, 0, stream>>>(Wres, nnz);
  sort_k<<<1, 1024, 0, stream>>>(nnz, rowsp, L1a, colmap);
  fill_k<<<256, 256, 0, stream>>>(Wres, rowsp, valw, col32);
  gemm_k<<<2048, 256, 0, stream>>>(A_pack, B_pack, colmap, out);
  reorder_k<<<4, 256, 0, stream>>>(valw, col32, L1a, val2, cw2);
  rnn_k<<<16, 1024, 0, stream>>>(out, init, val2, cw2, rowsp, L1a);
}

// Round 3
// 3255.229 us; speedup vs baseline: 1.1705x; 1.1705x over previous
//
#include <hip/hip_runtime.h>
#include <stdint.h>

typedef unsigned short u16;
typedef unsigned int   u32;
typedef __attribute__((ext_vector_type(8))) short short8;
typedef __attribute__((ext_vector_type(4))) float f32x4;

#define CAP   52

__device__ __forceinline__ u16 rne_bf16(float f){
  u32 u = __float_as_uint(f);
  u32 r = (u + 0x7fffu + ((u >> 16) & 1u)) >> 16;
  return (u16)r;
}
__device__ __forceinline__ float bf16_to_f(u16 h){
  return __uint_as_float(((u32)h) << 16);
}
__device__ __forceinline__ float tanh_fast(float x){
  float e = __expf(2.0f * x);
  return 1.0f - 2.0f / (e + 1.0f);
}

// ---------------------------------------------------------------------------
// A-pack: [xhi fbhi | xlo fblo], row m = b*1024+s, K=2048 bf16 bits
// ---------------------------------------------------------------------------
__global__ __launch_bounds__(256) void pack_a_k(const float* __restrict__ x,
                                                const float* __restrict__ fb,
                                                u16* __restrict__ A){
  int idx = blockIdx.x * 256 + threadIdx.x;          // 16384*512
  int m = idx >> 9, d = idx & 511;
  float xv = x[idx];
  float fv = fb[idx];
  u16 xh = rne_bf16(xv); u16 xl = rne_bf16(xv - bf16_to_f(xh));
  u16 fh = rne_bf16(fv); u16 fl = rne_bf16(fv - bf16_to_f(fh));
  size_t base = (size_t)m * 2048;
  A[base + d]        = xh;
  A[base + 512 + d]  = fh;
  A[base + 1024 + d] = xl;
  A[base + 1536 + d] = fl;
}

// ---------------------------------------------------------------------------
// B-pack with ROW PERMUTATION (row n of packed B = original row rowperm[n]).
// Drive then exits the GEMM already in rnn's permuted layout with plain
// coalesced stores (R2's colmap epilogue scattered 128 MB as 4B words).
// K=3072: [Winhi Wfbhi | Winhi Wfbhi | Winlo Wfblo]
// ---------------------------------------------------------------------------
__global__ __launch_bounds__(256) void pack_b_k(const float* __restrict__ Win,
                                                const float* __restrict__ Wfb,
                                                const int* __restrict__ rowperm,
                                                u16* __restrict__ Bm){
  int idx = blockIdx.x * 256 + threadIdx.x;          // 2048*512
  int n = idx >> 9, d = idx & 511;
  int row = rowperm[n];
  float iv = Win[(size_t)row * 512 + d];
  float fv = Wfb[(size_t)row * 512 + d];
  u16 ih = rne_bf16(iv); u16 il = rne_bf16(iv - bf16_to_f(ih));
  u16 fh = rne_bf16(fv); u16 fl = rne_bf16(fv - bf16_to_f(fh));
  size_t base = (size_t)n * 3072;
  Bm[base + d]        = ih;
  Bm[base + 512 + d]  = fh;
  Bm[base + 1024 + d] = ih;
  Bm[base + 1536 + d] = fh;
  Bm[base + 2048 + d] = il;
  Bm[base + 2560 + d] = fl;
}

// ---------------------------------------------------------------------------
// Drive GEMM: M=16384,N=2048,K=3072, 128x128 tile, plain coalesced stores.
// ---------------------------------------------------------------------------
#define GLDS(gp, lp) __builtin_amdgcn_global_load_lds( \
    (const __attribute__((address_space(1))) void*)(gp), \
    (__attribute__((address_space(3))) void*)(lp), 16, 0, 0)

__global__ __launch_bounds__(256) void gemm_k(const u16* __restrict__ A,
                                              const u16* __restrict__ Bm,
                                              float* __restrict__ C){
  __shared__ __align__(16) u16 As[128 * 32];
  __shared__ __align__(16) u16 Bs[128 * 32];
  const int tid = threadIdx.x;
  const int w = tid >> 6, l = tid & 63;
  const int bid = blockIdx.x;
  const int mt = bid >> 4, nt = bid & 15;
  const int m0 = mt * 128, n0 = nt * 128;
  const int srow = tid >> 2;
  const int scol = (tid & 3) * 8;
  const int wr = w & 1, wc = w >> 1;
  const int lhi = l >> 4, llo = l & 15;

  f32x4 acc[4][4];
  #pragma unroll
  for (int i = 0; i < 4; i++)
    #pragma unroll
    for (int j = 0; j < 4; j++)
      acc[i][j] = (f32x4){0.f, 0.f, 0.f, 0.f};

  for (int kt = 0; kt < 96; ++kt){
    int k = kt * 32;
    int keff = (k >= 2048) ? (k - 2048) : k;
    #pragma unroll
    for (int r = 0; r < 2; r++){
      const u16* ga = A  + (size_t)(m0 + r * 64 + srow) * 2048 + keff + scol;
      GLDS(ga, &As[r * 2048 + w * 512]);
      const u16* gb = Bm + (size_t)(n0 + r * 64 + srow) * 3072 + k + scol;
      GLDS(gb, &Bs[r * 2048 + w * 512]);
    }
    __syncthreads();
    short8 af[4], bf[4];
    #pragma unroll
    for (int i = 0; i < 4; i++){
      af[i] = *(const short8*)&As[(wr * 64 + i * 16 + llo) * 32 + lhi * 8];
      bf[i] = *(const short8*)&Bs[(wc * 64 + i * 16 + llo) * 32 + lhi * 8];
    }
    #pragma unroll
    for (int i = 0; i < 4; i++)
      #pragma unroll
      for (int j = 0; j < 4; j++)
        acc[i][j] = __builtin_amdgcn_mfma_f32_16x16x32_bf16(af[i], bf[j], acc[i][j], 0, 0, 0);
    __syncthreads();
  }
  #pragma unroll
  for (int i = 0; i < 4; i++)
    #pragma unroll
    for (int j = 0; j < 4; j++)
      #pragma unroll
      for (int rg = 0; rg < 4; rg++){
        int mr = m0 + wr * 64 + i * 16 + lhi * 4 + rg;
        int nc = n0 + wc * 64 + j * 16 + llo;
        C[(size_t)mr * 2048 + nc] = acc[i][j][rg];
      }
}

// ---------------------------------------------------------------------------
// count nnz per row (one wave per row)
// ---------------------------------------------------------------------------
__global__ __launch_bounds__(256) void count_k(const float* __restrict__ W,
                                               int* __restrict__ nnz){
  int gt = blockIdx.x * 256 + threadIdx.x;
  int row = gt >> 6, l = gt & 63;
  const float* wr = W + (size_t)row * 2048;
  int c = 0;
  for (int i = 0; i < 32; i++) c += (wr[i * 64 + l] != 0.0f) ? 1 : 0;
  for (int off = 32; off; off >>= 1) c += __shfl_down(c, off, 64);
  if (l == 0) nnz[row] = c;
}

// ---------------------------------------------------------------------------
// Counting-sort rows desc by nnz, pair p <-> 2047-p; emit rowperm for pack_b.
// ---------------------------------------------------------------------------
__global__ __launch_bounds__(1024) void sort_k(const int* __restrict__ nnz,
                                               u32* __restrict__ rowsp,
                                               int* __restrict__ L1a,
                                               int* __restrict__ rowperm){
  __shared__ int hist[64], off[64], cur[64];
  __shared__ int order[2048];
  int tid = threadIdx.x;
  if (tid < 64){ hist[tid] = 0; cur[tid] = 0; }
  __syncthreads();
  for (int r = tid; r < 2048; r += 1024){
    int b = nnz[r]; if (b > 63) b = 63;
    atomicAdd(&hist[b], 1);
  }
  __syncthreads();
  if (tid == 0){
    int run = 0;
    for (int b = 63; b >= 0; b--){ off[b] = run; run += hist[b]; }
  }
  __syncthreads();
  for (int r = tid; r < 2048; r += 1024){
    int b = nnz[r]; if (b > 63) b = 63;
    int pos = off[b] + atomicAdd(&cur[b], 1);
    order[pos] = r;
  }
  __syncthreads();
  int rA = order[tid], rB = order[2047 - tid];
  rowsp[tid] = (u32)rA | ((u32)rB << 16);
  L1a[tid] = nnz[rA];
  rowperm[tid] = rA;
  rowperm[tid + 1024] = rB;
}

// ---------------------------------------------------------------------------
// Fill per-thread item words (slot-major): [0,L1)=rowA, [L1,..)=rowB, pad 0.
// Item word = (f32 W bits rounded to 10-bit mantissa, bits 31:13)
//           | (col*4 in bits 12:2).  One u32 per item -> 52 VGPRs in rnn.
// ---------------------------------------------------------------------------
__global__ __launch_bounds__(256) void fill_k(const float* __restrict__ W,
                                              const u32* __restrict__ rowsp,
                                              u32* __restrict__ wpk){
  int gt = blockIdx.x * 256 + threadIdx.x;
  int p = gt >> 6, l = gt & 63;
  u32 rp = rowsp[p];
  int rA = (int)(rp & 0xffffu), rB = (int)(rp >> 16);
  int base = 0;
  for (int h = 0; h < 2; h++){
    int row = h ? rB : rA;
    const float* wr = W + (size_t)row * 2048;
    int cnt = 0;
    for (int i = 0; i < 32; i++){
      int c = i * 64 + l;
      float v = wr[c];
      unsigned long long m = __ballot(v != 0.0f);
      int pre = __popcll(m & ((1ull << l) - 1ull));
      if (v != 0.0f){
        int s = base + cnt + pre;
        if (s < CAP){
          u32 u = __float_as_uint(v);
          u = (u + 0x1000u) & 0xFFFFE000u;       // round-to-nearest, 10-bit mant
          wpk[s * 1024 + p] = u | ((u32)c << 2); // byte offset in bits 12:2
        }
      }
      cnt += __popcll(m);
    }
    base += cnt;
  }
  for (int s = base + l; s < CAP; s += 64)
    wpk[s * 1024 + p] = 0u;                      // val=0, col=0 (broadcast read)
}

// ---------------------------------------------------------------------------
// Recurrent kernel: 16 WGs (1 batch/CU), 1024 thr, state in LDS, sparse W as
// 52 packed u32 in REGISTERS. amdgpu_waves_per_eu(4,4) forces the VGPR budget
// to 128 (launch_bounds(1024,4) was ignored in R2 -> VGPR=64 -> every step
// re-loaded 78 words/thread from memory = the 7300 cyc/step floor).
// ---------------------------------------------------------------------------
__global__ __attribute__((amdgpu_flat_work_group_size(1024, 1024),
                          amdgpu_waves_per_eu(4, 4)))
void rnn_k(float* __restrict__ out,
           const float* __restrict__ init,
           const u32* __restrict__ wpkg,
           const u32* __restrict__ rowsp,
           const int* __restrict__ L1a){
  const int tid = threadIdx.x, b = blockIdx.x;
  u32 wk[CAP];
  #pragma unroll
  for (int k = 0; k < CAP; k++) wk[k] = wpkg[k * 1024 + tid];
  u32 rp = rowsp[tid];
  int rA = (int)(rp & 0xffffu), rB = (int)(rp >> 16);
  int L1 = L1a[tid];

  __shared__ float st[2048];
  st[tid]        = init[(size_t)b * 2048 + tid];
  st[tid + 1024] = init[(size_t)b * 2048 + tid + 1024];
  __syncthreads();
  const char* stb = (const char*)st;

  float* ob = out + (size_t)b * 1024 * 2048;
  float dA = __builtin_nontemporal_load(&ob[tid]);
  float dB = __builtin_nontemporal_load(&ob[tid + 1024]);
  for (int t = 0; t < 1024; t++){
    float* orow = ob + (size_t)t * 2048;
    const float* nrow = ob + (size_t)((t + 1) & 1023) * 2048;
    float dA2 = __builtin_nontemporal_load(&nrow[tid]);        // prefetch t+1
    float dB2 = __builtin_nontemporal_load(&nrow[tid + 1024]);
    float aAll = 0.f, aA = 0.f;
    #pragma unroll
    for (int k = 0; k < CAP; k++){
      u32 w = wk[k];
      float sv = *(const float*)(stb + (w & 0x1FFCu));
      float pv = __uint_as_float(w & 0xFFFFE000u) * sv;
      aAll += pv;
      aA += (k < L1) ? pv : 0.0f;
    }
    float preA = aA + dA;                 // consume drive BEFORE barrier
    float preB = (aAll - aA) + dB;
    __syncthreads();                      // all st reads done
    float sA = tanh_fast(preA);
    float sB = tanh_fast(preB);
    st[rA] = sA; st[rB] = sB;
    __syncthreads();                      // new state visible
    __builtin_nontemporal_store(st[tid], &orow[tid]);          // coalesced
    __builtin_nontemporal_store(st[tid + 1024], &orow[tid + 1024]);
    dA = dA2; dB = dB2;
  }
}

// ---------------------------------------------------------------------------
extern "C" void kernel_launch(void* const* d_in, const int* in_sizes, int n_in,
                              void* d_out, int out_size, void* d_ws, size_t ws_size,
                              hipStream_t stream) {
  const float* x    = (const float*)d_in[0];
  const float* fb   = (const float*)d_in[1];
  const float* init = (const float*)d_in[2];
  const float* Wres = (const float*)d_in[3];
  const float* Win  = (const float*)d_in[4];
  const float* Wfb  = (const float*)d_in[5];
  float* out = (float*)d_out;

  char* w8 = (char*)d_ws;
  u16*  A_pack = (u16*)(w8);                       // 67108864 B
  u16*  B_pack = (u16*)(w8 + 67108864);            // 12582912 B
  u32*  wpk    = (u32*) (w8 + 79691776);           // 52*1024*4 = 212992
  int*  nnz    = (int*) (w8 + 79904768);           // 8192
  u32*  rowsp  = (u32*) (w8 + 79912960);           // 4096
  int*  L1a    = (int*) (w8 + 79917056);           // 4096
  int*  rowperm= (int*) (w8 + 79921152);           // 8192

  pack_a_k<<<32768, 256, 0, stream>>>(x, fb, A_pack);
  count_k<<<512, 256, 0, stream>>>(Wres, nnz);
  sort_k<<<1, 1024, 0, stream>>>(nnz, rowsp, L1a, rowperm);
  pack_b_k<<<4096, 256, 0, stream>>>(Win, Wfb, rowperm, B_pack);
  fill_k<<<256, 256, 0, stream>>>(Wres, rowsp, wpk);
  gemm_k<<<2048, 256, 0, stream>>>(A_pack, B_pack, out);
  rnn_k<<<16, 1024, 0, stream>>>(out, init, wpk, rowsp, L1a);
}